// Round 12
// baseline (1246.276 us; speedup 1.0000x reference)
//
#include <hip/hip_runtime.h>

// ---------------------------------------------------------------------------
// Actor: GRU over V=20 vehicle slots (H=256) + MLP head 271->1024->1024->512->256->1
// B=16384, F=15. All GEMMs in bf16 MFMA (16x16x32), fp32 accumulate.
//
// Round-12: 2D wave tiling for the GRU. 16 waves = 4 col-groups x 4 row-
// groups; wave (cg,rg) computes r,z,n for j in [cg*64,cg*64+64) x rows
// [rg*16,rg*16+16). Per-wave LDS h-reads drop 4x (8KB/pass vs 32KB) ->
// 0.29 MB/CU/step vs r11's 1.05 MB. Same gate-split 2-pass (32 acc regs,
// fits the empirical 64-VGPR wg-1024 budget), same rzbuf[jq][tid] per-lane
// scratch, same numerics as r11.
// ---------------------------------------------------------------------------

typedef __attribute__((ext_vector_type(8))) __bf16 bf16x8;
typedef __attribute__((ext_vector_type(4))) __bf16 bf16x4;
typedef __attribute__((ext_vector_type(4))) float  floatx4;

#define MFMA16(a, b, c) __builtin_amdgcn_mfma_f32_16x16x32_bf16((a), (b), (c), 0, 0, 0)

#define GL_LDS16(g, l)                                                         \
    __builtin_amdgcn_global_load_lds(                                          \
        (const __attribute__((address_space(1))) void*)(g),                    \
        (__attribute__((address_space(3))) void*)(l), 16, 0, 0)

__device__ __forceinline__ float sigmoid_f(float x) { return 1.f / (1.f + __expf(-x)); }
__device__ __forceinline__ float tanh_f(float x)    { return 1.f - 2.f / (1.f + __expf(2.f * x)); }

// ---------------------------------------------------------------------------
// Weight prep:
//   Wg1  [512][288]  rows g in {r(0..255), z(256..511)}:
//        [W_ih[g][0..14] | bsum[g] | 0 x16 | W_hh[g][0..255]]   (col 15 = bias)
//   W1p  [1024][288] : [W1[o][0..14] | 0 x17 | W1[o][15..270]]
//   W2b  [1024][1024], W3b [512][1024], W4b [256][512]  : direct cvt
//   Win_n[256][32]   : [W_ih[512+j][0..14] | b_ih[512+j] | 0 x16] (col 15 = bias)
//   Whh_n[256][256]  : W_hh rows 512..767
//   bhhn [256] = b_hh[512+]
// ---------------------------------------------------------------------------
#define S0 147456u
#define S1 442368u
#define S2 1490944u
#define S3 2015232u
#define S4 2146304u
#define S5 2154496u
#define S6 2220032u
#define S7 2220544u
#define S8 2221056u

__global__ void prep_kernel(const float* __restrict__ W_ih, const float* __restrict__ W_hh,
                            const float* __restrict__ b_ih, const float* __restrict__ b_hh,
                            const float* __restrict__ W1, const float* __restrict__ W2,
                            const float* __restrict__ W3, const float* __restrict__ W4,
                            __bf16* __restrict__ Wg1, __bf16* __restrict__ W1p,
                            __bf16* __restrict__ W2b, __bf16* __restrict__ W3b,
                            __bf16* __restrict__ W4b, __bf16* __restrict__ Win_n,
                            __bf16* __restrict__ Whh_n, float* __restrict__ bsum,
                            float* __restrict__ bihn, float* __restrict__ bhhn)
{
    for (unsigned i = blockIdx.x * blockDim.x + threadIdx.x; i < S8; i += gridDim.x * blockDim.x) {
        if (i < S0) {
            unsigned g = i / 288u, c = i % 288u;
            float v;
            if (c < 15u)       v = W_ih[g * 15u + c];
            else if (c == 15u) v = b_ih[g] + b_hh[g];          // folded r/z bias
            else if (c < 32u)  v = 0.f;
            else               v = W_hh[g * 256u + (c - 32u)];
            Wg1[i] = (__bf16)v;
        } else if (i < S1) {
            unsigned t = i - S0, o = t / 288u, c = t % 288u;
            float v = (c < 15u) ? W1[o * 271u + c] : ((c < 32u) ? 0.f : W1[o * 271u + (c - 17u)]);
            W1p[t] = (__bf16)v;
        } else if (i < S2) {
            unsigned t = i - S1; W2b[t] = (__bf16)W2[t];
        } else if (i < S3) {
            unsigned t = i - S2; W3b[t] = (__bf16)W3[t];
        } else if (i < S4) {
            unsigned t = i - S3; W4b[t] = (__bf16)W4[t];
        } else if (i < S5) {
            unsigned t = i - S4, j = t / 32u, c = t % 32u;
            float v;
            if (c < 15u)       v = W_ih[(512u + j) * 15u + c];
            else if (c == 15u) v = b_ih[512u + j];             // folded xn bias
            else               v = 0.f;
            Win_n[t] = (__bf16)v;
        } else if (i < S6) {
            unsigned t = i - S5; Whh_n[t] = (__bf16)W_hh[512u * 256u + t];
        } else if (i < S7) {
            unsigned t = i - S6; bsum[t] = b_ih[t] + b_hh[t];
        } else {
            unsigned t = i - S7;
            if (t < 256u) bihn[t] = b_ih[512u + t];
            else          bhhn[t - 256u] = b_hh[512u + t - 256u];
        }
    }
}

// ---------------------------------------------------------------------------
// GRU kernel. 256 blocks x 1024 threads (16 waves = 4 cg x 4 rg).
// Wave (cg,rg): gates j in [cg*64, cg*64+64) for rows [rg*16, rg*16+16).
// Per step, 2 unroll-1 passes:
//   p0: acc (ar,az) over 4 j-quarters (32 regs) -> sigmoid -> rzbuf[jq][tid]
//   p1: acc (axn,ahn) (32 regs) -> n=tanh(axn+r*(ahn+bhn)), h'=(1-z)n+z*h_old
// hbuf[2][64][264] double-buffered, 1 barrier/step.
// ---------------------------------------------------------------------------
#define HSTRIDE 264
#define HBUF_N  (64 * HSTRIDE)

__global__ __launch_bounds__(1024)
void gru_kernel(const float* __restrict__ state,
                const __bf16* __restrict__ Wg1,  const __bf16* __restrict__ Win_n,
                const __bf16* __restrict__ Whh_n,
                const float* __restrict__ bhhn, __bf16* __restrict__ x0)
{
    __shared__ __bf16 hbuf[2 * HBUF_N];        // 67584 B
    __shared__ __bf16 sbuf[2 * 2048];          // 8192 B; k 16..31 zero, k15 = 1.0
    __shared__ __bf16 rzbuf[4 * 1024 * 8];     // 65536 B: [jq][tid][8] r0..3|z0..3

    const int tid  = threadIdx.x;
    const int wave = tid >> 6;
    const int cg   = wave >> 2;   // 0..3 col-group (64 gate cols)
    const int rg   = wave & 3;    // 0..3 row-group (16 batch rows)
    const int lane = tid & 63;
    const int q    = lane >> 4;
    const int ln   = lane & 15;
    const int b0   = blockIdx.x * 64;

    {   // zero h buffer 0 and both sbuf buffers
        bf16x8 z = {};
        bf16x8* p = (bf16x8*)hbuf;
        #pragma unroll 3
        for (int i = tid; i < HBUF_N / 8; i += 1024) p[i] = z;
        if (tid < 512) ((bf16x8*)sbuf)[tid] = z;
    }
    const int srow = tid >> 4, sk = tid & 15;   // 64 rows x 16 cols staging

    // weight bases for this wave's col-group (A-operand rows; + jq offsets)
    const __bf16* wrB = Wg1   + (size_t)(cg * 64 + ln) * 288 + q * 8;        // + jq*4608
    const __bf16* wzB = Wg1   + (size_t)(256 + cg * 64 + ln) * 288 + q * 8;  // + jq*4608
    const __bf16* wxB = Win_n + (size_t)(cg * 64 + ln) * 32  + q * 8;        // + jq*512
    const __bf16* whB = Whh_n + (size_t)(cg * 64 + ln) * 256 + q * 8;        // + jq*4096
    const float*  bhnB = bhhn + cg * 64 + q * 4;                             // + jq*16

    const int row = rg * 16 + ln;
    const __bf16* hread = hbuf + row * HSTRIDE + q * 8;            // + kk*32, + SB*HBUF_N
    __bf16*       hwrt  = hbuf + row * HSTRIDE + cg * 64 + q * 4;  // + jq*16, + buf*HBUF_N
    const __bf16* sread = sbuf + row * 32 + q * 8;                 // + SB*2048
    __bf16*       rzw   = rzbuf + tid * 8;                         // + jq*8192

    // stage state slice v=0, then set the permanent 1.0 bias column (k=15)
    if (sk < 15)
        sbuf[srow * 32 + sk] = (__bf16)state[(size_t)(b0 + srow) * 300 + sk];
    if (tid < 128) sbuf[(tid >> 6) * 2048 + (tid & 63) * 32 + 15] = (__bf16)1.0f;
    __syncthreads();

#define GRU_STEP(v, SB)                                                          \
    {                                                                            \
        float snext = 0.f;                                                       \
        if ((v) < 19 && sk < 15)                                                 \
            snext = state[(size_t)(b0 + srow) * 300 + ((v) + 1) * 15 + sk];      \
        _Pragma("unroll 1")                                                      \
        for (int p = 0; p < 2; ++p) {                                            \
            floatx4 acc0[4], acc1[4];                                            \
            const floatx4 zf = {0.f, 0.f, 0.f, 0.f};                             \
            _Pragma("unroll")                                                    \
            for (int jq = 0; jq < 4; jq++) { acc0[jq] = zf; acc1[jq] = zf; }     \
            if (p == 0) {                                                        \
                {                                                                \
                    bf16x8 b = *(const bf16x8*)(sread + (SB) * 2048);            \
                    _Pragma("unroll")                                            \
                    for (int jq = 0; jq < 4; jq++) {                             \
                        bf16x8 a0 = *(const bf16x8*)(wrB + jq * 4608);           \
                        bf16x8 a1 = *(const bf16x8*)(wzB + jq * 4608);           \
                        acc0[jq] = MFMA16(a0, b, acc0[jq]);                      \
                        acc1[jq] = MFMA16(a1, b, acc1[jq]);                      \
                    }                                                            \
                }                                                                \
                _Pragma("unroll")                                                \
                for (int kk = 0; kk < 8; ++kk) {                                 \
                    bf16x8 b = *(const bf16x8*)(hread + (SB) * HBUF_N +          \
                                                kk * 32);                        \
                    _Pragma("unroll")                                            \
                    for (int jq = 0; jq < 4; jq++) {                             \
                        bf16x8 a0 = *(const bf16x8*)(wrB + jq * 4608 + 32 +      \
                                                     kk * 32);                   \
                        bf16x8 a1 = *(const bf16x8*)(wzB + jq * 4608 + 32 +      \
                                                     kk * 32);                   \
                        acc0[jq] = MFMA16(a0, b, acc0[jq]);                      \
                        acc1[jq] = MFMA16(a1, b, acc1[jq]);                      \
                    }                                                            \
                }                                                                \
                _Pragma("unroll")                                                \
                for (int jq = 0; jq < 4; jq++) {                                 \
                    bf16x8 rz;                                                   \
                    _Pragma("unroll")                                            \
                    for (int r = 0; r < 4; r++) {                                \
                        rz[r]     = (__bf16)sigmoid_f(acc0[jq][r]);              \
                        rz[4 + r] = (__bf16)sigmoid_f(acc1[jq][r]);              \
                    }                                                            \
                    *(bf16x8*)(rzw + jq * 8192) = rz;                            \
                }                                                                \
            } else {                                                             \
                {                                                                \
                    bf16x8 b = *(const bf16x8*)(sread + (SB) * 2048);            \
                    _Pragma("unroll")                                            \
                    for (int jq = 0; jq < 4; jq++) {                             \
                        bf16x8 a = *(const bf16x8*)(wxB + jq * 512);             \
                        acc0[jq] = MFMA16(a, b, acc0[jq]);                       \
                    }                                                            \
                }                                                                \
                _Pragma("unroll")                                                \
                for (int kk = 0; kk < 8; ++kk) {                                 \
                    bf16x8 b = *(const bf16x8*)(hread + (SB) * HBUF_N +          \
                                                kk * 32);                        \
                    _Pragma("unroll")                                            \
                    for (int jq = 0; jq < 4; jq++) {                             \
                        bf16x8 a = *(const bf16x8*)(whB + jq * 4096 + kk * 32);  \
                        acc1[jq] = MFMA16(a, b, acc1[jq]);                       \
                    }                                                            \
                }                                                                \
                _Pragma("unroll")                                                \
                for (int jq = 0; jq < 4; jq++) {                                 \
                    bf16x8 rz = *(const bf16x8*)(rzw + jq * 8192);               \
                    floatx4 bh = *(const floatx4*)(bhnB + jq * 16);              \
                    bf16x4 ho = *(const bf16x4*)(hwrt + (SB) * HBUF_N +          \
                                                 jq * 16);                       \
                    bf16x4 hv;                                                   \
                    _Pragma("unroll")                                            \
                    for (int r = 0; r < 4; r++) {                                \
                        float rg_ = (float)rz[r];                                \
                        float zg  = (float)rz[4 + r];                            \
                        float nn = tanh_f(acc0[jq][r] +                          \
                                          rg_ * (acc1[jq][r] + bh[r]));          \
                        float hnew = (1.f - zg) * nn + zg * (float)ho[r];        \
                        hv[r] = (__bf16)hnew;                                    \
                    }                                                            \
                    *(bf16x4*)(hwrt + (1 - (SB)) * HBUF_N + jq * 16) = hv;       \
                }                                                                \
            }                                                                    \
        }                                                                        \
        if ((v) < 19 && sk < 15)                                                 \
            sbuf[(1 - (SB)) * 2048 + srow * 32 + sk] = (__bf16)snext;            \
        __syncthreads();                                                         \
    }

    #pragma unroll 1
    for (int v2 = 0; v2 < 10; ++v2) {
        GRU_STEP(2 * v2,     0)
        GRU_STEP(2 * v2 + 1, 1)
    }
#undef GRU_STEP

    // ---- epilogue: final h is in hbuf buffer 0 (step 19 wrote 1-SB = 0) ----
    // x0 = [state[:,0,:] (15) | 0-pad to 32 | h (256)], coalesced b128 moves.
    {
        const int erow = tid >> 4, p = tid & 15;
        #pragma unroll
        for (int s = 0; s < 2; s++) {
            const int col = p * 8 + s * 128;
            *(bf16x8*)(x0 + (size_t)(b0 + erow) * 288 + 32 + col) =
                *(const bf16x8*)(hbuf + erow * HSTRIDE + col);
        }
    }
    #pragma unroll
    for (int t = 0; t < 2; t++) {
        int i = tid + t * 1024;
        int erow = i >> 5, c = i & 31;
        float s = (c < 15) ? state[(size_t)(b0 + erow) * 300 + c] : 0.f;
        x0[(size_t)(b0 + erow) * 288 + c] = (__bf16)s;
    }
}

// ---------------------------------------------------------------------------
// m97-style LDS-staged GEMM: C = act(A[M][K] @ W[N][K]^T + bias), bf16, BK=32.
// 256 thr (4 waves 2x2), tile 128x128. Staging via global_load_lds width=16.
// Epilogue: LDS bounce -> coalesced stores.
// ---------------------------------------------------------------------------
__global__ __launch_bounds__(256)
void gemm_bias_act(const __bf16* __restrict__ A, const __bf16* __restrict__ W,
                   const float* __restrict__ bias, __bf16* __restrict__ C,
                   int N, int K, int relu)
{
    __shared__ __bf16 smem[128 * 136];           // 34816 B
    __bf16* At = smem;                           // [128][32]
    __bf16* Bt = smem + 4096;                    // [128][32]

    const int tid  = threadIdx.x;
    const int wave = tid >> 6, lane = tid & 63;
    const int q = lane >> 4, ln = lane & 15;
    const int wm = wave >> 1, wn = wave & 1;
    const int arow0 = blockIdx.x * 128;
    const int bcol0 = blockIdx.y * 128;

    float bv[4];
    #pragma unroll
    for (int n = 0; n < 4; n++) bv[n] = bias[bcol0 + wn * 64 + n * 16 + ln];

    floatx4 acc[4][4];
    const floatx4 zf = {0.f, 0.f, 0.f, 0.f};
    #pragma unroll
    for (int m = 0; m < 4; m++)
        #pragma unroll
        for (int n = 0; n < 4; n++) acc[m][n] = zf;

    const int stg_row = wave * 16 + (lane >> 2);
    const int stg_k   = (lane & 3) * 8;
    const int lds_off = wave * 512;

    for (int kt = 0; kt < K; kt += 32) {
        #pragma unroll
        for (int rd = 0; rd < 2; rd++) {
            GL_LDS16(A + (size_t)(arow0 + stg_row + rd * 64) * K + kt + stg_k,
                     At + lds_off + rd * 2048);
            GL_LDS16(W + (size_t)(bcol0 + stg_row + rd * 64) * K + kt + stg_k,
                     Bt + lds_off + rd * 2048);
        }
        __syncthreads();
        bf16x8 af[4], bf[4];
        #pragma unroll
        for (int m = 0; m < 4; m++)
            af[m] = *(const bf16x8*)(At + (wm * 64 + m * 16 + ln) * 32 + q * 8);
        #pragma unroll
        for (int n = 0; n < 4; n++)
            bf[n] = *(const bf16x8*)(Bt + (wn * 64 + n * 16 + ln) * 32 + q * 8);
        #pragma unroll
        for (int n = 0; n < 4; n++)
            #pragma unroll
            for (int m = 0; m < 4; m++)
                acc[m][n] = MFMA16(af[m], bf[n], acc[m][n]);
        __syncthreads();
    }

    #pragma unroll
    for (int m = 0; m < 4; m++)
        #pragma unroll
        for (int n = 0; n < 4; n++)
            #pragma unroll
            for (int r = 0; r < 4; r++) {
                float val = acc[m][n][r] + bv[n];
                if (relu) val = fmaxf(val, 0.f);
                smem[(wm * 64 + m * 16 + q * 4 + r) * 136 + wn * 64 + n * 16 + ln] = (__bf16)val;
            }
    __syncthreads();
    {
        const int row = tid >> 4, seg = tid & 15;
        #pragma unroll
        for (int p = 0; p < 8; p++) {
            const int rr = row + p * 16;
            *(bf16x8*)(C + (size_t)(arow0 + rr) * N + bcol0 + seg * 8) =
                *(const bf16x8*)(smem + rr * 136 + seg * 8);
        }
    }
}

// ---------------------------------------------------------------------------
// Head: out[b] = tanh(dot(x4[b][0..255], Wp) + bp).  4 lanes per row.
// ---------------------------------------------------------------------------
__global__ __launch_bounds__(256)
void head_kernel(const __bf16* __restrict__ x4, const float* __restrict__ Wp,
                 const float* __restrict__ bp, float* __restrict__ out)
{
    const int tid = threadIdx.x;
    const int wave = tid >> 6, lane = tid & 63;
    const int row = blockIdx.x * 64 + wave * 16 + (lane >> 2);
    const int part = lane & 3;
    const __bf16* xp = x4 + (size_t)row * 256 + part * 64;
    const float* wp = Wp + part * 64;
    float sum = 0.f;
    #pragma unroll
    for (int i = 0; i < 8; i++) {
        bf16x8 xv = *(const bf16x8*)(xp + i * 8);
        #pragma unroll
        for (int jj = 0; jj < 8; jj++) sum += (float)xv[jj] * wp[i * 8 + jj];
    }
    sum += __shfl_xor(sum, 1);
    sum += __shfl_xor(sum, 2);
    if (part == 0) out[row] = tanhf(sum + bp[0]);
}

// ---------------------------------------------------------------------------
extern "C" void kernel_launch(void* const* d_in, const int* in_sizes, int n_in,
                              void* d_out, int out_size, void* d_ws, size_t ws_size,
                              hipStream_t stream)
{
    const float* state = (const float*)d_in[0];
    const float* W_ih  = (const float*)d_in[1];
    const float* W_hh  = (const float*)d_in[2];
    const float* b_ih  = (const float*)d_in[3];
    const float* b_hh  = (const float*)d_in[4];
    const float* W1    = (const float*)d_in[5];
    const float* b1    = (const float*)d_in[6];
    const float* W2    = (const float*)d_in[7];
    const float* b2    = (const float*)d_in[8];
    const float* W3    = (const float*)d_in[9];
    const float* b3    = (const float*)d_in[10];
    const float* W4    = (const float*)d_in[11];
    const float* b4    = (const float*)d_in[12];
    const float* Wp    = (const float*)d_in[13];
    const float* bp    = (const float*)d_in[14];
    float* out = (float*)d_out;

    char* ws = (char*)d_ws;
    size_t off = 0;
    auto alloc = [&](size_t bytes) -> void* {
        void* p = ws + off;
        off += (bytes + 255) & ~(size_t)255;
        return p;
    };
    __bf16* Wg1   = (__bf16*)alloc(512 * 288 * 2);
    __bf16* W1p   = (__bf16*)alloc(1024 * 288 * 2);
    __bf16* W2b   = (__bf16*)alloc(1024 * 1024 * 2);
    __bf16* W3b   = (__bf16*)alloc(512 * 1024 * 2);
    __bf16* W4b   = (__bf16*)alloc(256 * 512 * 2);
    __bf16* Win_n = (__bf16*)alloc(256 * 32 * 2);
    __bf16* Whh_n = (__bf16*)alloc(256 * 256 * 2);
    float*  bsum  = (float*)alloc(512 * 4);
    float*  bihn  = (float*)alloc(256 * 4);
    float*  bhhn  = (float*)alloc(256 * 4);
    __bf16* x0    = (__bf16*)alloc((size_t)16384 * 288 * 2);
    __bf16* xA    = (__bf16*)alloc((size_t)16384 * 1024 * 2);
    __bf16* xB    = (__bf16*)alloc((size_t)16384 * 1024 * 2);

    prep_kernel<<<2048, 256, 0, stream>>>(W_ih, W_hh, b_ih, b_hh, W1, W2, W3, W4,
                                          Wg1, W1p, W2b, W3b, W4b, Win_n, Whh_n,
                                          bsum, bihn, bhhn);
    gru_kernel<<<256, 1024, 0, stream>>>(state, Wg1, Win_n, Whh_n, bhhn, x0);
    gemm_bias_act<<<dim3(128, 8), 256, 0, stream>>>(x0, W1p, b1, xA, 1024, 288, 1);
    gemm_bias_act<<<dim3(128, 8), 256, 0, stream>>>(xA, W2b, b2, xB, 1024, 1024, 1);
    gemm_bias_act<<<dim3(128, 4), 256, 0, stream>>>(xB, W3b, b3, xA, 512, 1024, 1);
    gemm_bias_act<<<dim3(128, 2), 256, 0, stream>>>(xA, W4b, b4, xB, 256, 512, 1);
    head_kernel<<<256, 256, 0, stream>>>(xB, Wp, bp, out);
}

// Round 13
// 874.453 us; speedup vs baseline: 1.4252x; 1.4252x over previous
//
#include <hip/hip_runtime.h>

// ---------------------------------------------------------------------------
// Actor: GRU over V=20 vehicle slots (H=256) + MLP head 271->1024->1024->512->256->1
// B=16384, F=15. All GEMMs in bf16 MFMA (16x16x32), fp32 accumulate.
//
// Round-13: r11 gate-split base, re-tiled to 512 blocks x 32 rows; 16 waves =
// 8 col-groups x 2 row-groups. Wave = 32 j-cols (2 jq) x 16 rows. Per pass:
// acc 16 regs + 4 weight frags (16) -> ~45 live, far under the empirical
// 64-VGPR wg-1024 budget (r12 spilled because 4jq x 2 gates = 32 regs of
// weight transients). LDS h-reads halve; 2 blocks/CU -> 8 waves/SIMD and
// cross-block barrier overlap. Weight L2 stream doubles (864 KB/CU/step,
// ~14K cyc floor) but stays under the L2 ceiling.
// ---------------------------------------------------------------------------

typedef __attribute__((ext_vector_type(8))) __bf16 bf16x8;
typedef __attribute__((ext_vector_type(4))) __bf16 bf16x4;
typedef __attribute__((ext_vector_type(4))) float  floatx4;

#define MFMA16(a, b, c) __builtin_amdgcn_mfma_f32_16x16x32_bf16((a), (b), (c), 0, 0, 0)

#define GL_LDS16(g, l)                                                         \
    __builtin_amdgcn_global_load_lds(                                          \
        (const __attribute__((address_space(1))) void*)(g),                    \
        (__attribute__((address_space(3))) void*)(l), 16, 0, 0)

__device__ __forceinline__ float sigmoid_f(float x) { return 1.f / (1.f + __expf(-x)); }
__device__ __forceinline__ float tanh_f(float x)    { return 1.f - 2.f / (1.f + __expf(2.f * x)); }

// ---------------------------------------------------------------------------
// Weight prep:
//   Wg1  [512][288]  rows g in {r(0..255), z(256..511)}:
//        [W_ih[g][0..14] | bsum[g] | 0 x16 | W_hh[g][0..255]]   (col 15 = bias)
//   W1p  [1024][288] : [W1[o][0..14] | 0 x17 | W1[o][15..270]]
//   W2b  [1024][1024], W3b [512][1024], W4b [256][512]  : direct cvt
//   Win_n[256][32]   : [W_ih[512+j][0..14] | b_ih[512+j] | 0 x16] (col 15 = bias)
//   Whh_n[256][256]  : W_hh rows 512..767
//   bhhn [256] = b_hh[512+]
// ---------------------------------------------------------------------------
#define S0 147456u
#define S1 442368u
#define S2 1490944u
#define S3 2015232u
#define S4 2146304u
#define S5 2154496u
#define S6 2220032u
#define S7 2220544u
#define S8 2221056u

__global__ void prep_kernel(const float* __restrict__ W_ih, const float* __restrict__ W_hh,
                            const float* __restrict__ b_ih, const float* __restrict__ b_hh,
                            const float* __restrict__ W1, const float* __restrict__ W2,
                            const float* __restrict__ W3, const float* __restrict__ W4,
                            __bf16* __restrict__ Wg1, __bf16* __restrict__ W1p,
                            __bf16* __restrict__ W2b, __bf16* __restrict__ W3b,
                            __bf16* __restrict__ W4b, __bf16* __restrict__ Win_n,
                            __bf16* __restrict__ Whh_n, float* __restrict__ bsum,
                            float* __restrict__ bihn, float* __restrict__ bhhn)
{
    for (unsigned i = blockIdx.x * blockDim.x + threadIdx.x; i < S8; i += gridDim.x * blockDim.x) {
        if (i < S0) {
            unsigned g = i / 288u, c = i % 288u;
            float v;
            if (c < 15u)       v = W_ih[g * 15u + c];
            else if (c == 15u) v = b_ih[g] + b_hh[g];          // folded r/z bias
            else if (c < 32u)  v = 0.f;
            else               v = W_hh[g * 256u + (c - 32u)];
            Wg1[i] = (__bf16)v;
        } else if (i < S1) {
            unsigned t = i - S0, o = t / 288u, c = t % 288u;
            float v = (c < 15u) ? W1[o * 271u + c] : ((c < 32u) ? 0.f : W1[o * 271u + (c - 17u)]);
            W1p[t] = (__bf16)v;
        } else if (i < S2) {
            unsigned t = i - S1; W2b[t] = (__bf16)W2[t];
        } else if (i < S3) {
            unsigned t = i - S2; W3b[t] = (__bf16)W3[t];
        } else if (i < S4) {
            unsigned t = i - S3; W4b[t] = (__bf16)W4[t];
        } else if (i < S5) {
            unsigned t = i - S4, j = t / 32u, c = t % 32u;
            float v;
            if (c < 15u)       v = W_ih[(512u + j) * 15u + c];
            else if (c == 15u) v = b_ih[512u + j];             // folded xn bias
            else               v = 0.f;
            Win_n[t] = (__bf16)v;
        } else if (i < S6) {
            unsigned t = i - S5; Whh_n[t] = (__bf16)W_hh[512u * 256u + t];
        } else if (i < S7) {
            unsigned t = i - S6; bsum[t] = b_ih[t] + b_hh[t];
        } else {
            unsigned t = i - S7;
            if (t < 256u) bihn[t] = b_ih[512u + t];
            else          bhhn[t - 256u] = b_hh[512u + t - 256u];
        }
    }
}

// ---------------------------------------------------------------------------
// GRU kernel. 512 blocks x 1024 threads (16 waves = 8 cg x 2 rg), 32 batch
// rows/block, 2 blocks/CU. Wave (cg,rg): gates j in [cg*32, cg*32+32) for
// rows [rg*16, rg*16+16). Per step, 2 unroll-1 passes:
//   p0: acc (ar,az) x 2 jq (16 regs) -> sigmoid -> rzbuf[jq][tid]
//   p1: acc (axn,ahn) x 2 jq -> n=tanh(axn+r*(ahn+bhn)), h'=(1-z)n+z*h_old
// hbuf[2][32][264] double-buffered, 1 barrier/step. LDS 70.7 KB.
// ---------------------------------------------------------------------------
#define HSTRIDE 264
#define HBUF_N  (32 * HSTRIDE)

__global__ __launch_bounds__(1024)
void gru_kernel(const float* __restrict__ state,
                const __bf16* __restrict__ Wg1,  const __bf16* __restrict__ Win_n,
                const __bf16* __restrict__ Whh_n,
                const float* __restrict__ bhhn, __bf16* __restrict__ x0)
{
    __shared__ __bf16 hbuf[2 * HBUF_N];        // 33792 B
    __shared__ __bf16 sbuf[2 * 1024];          // 4096 B; k 16..31 zero, k15 = 1.0
    __shared__ __bf16 rzbuf[2 * 1024 * 8];     // 32768 B: [jq][tid][8] r0..3|z0..3

    const int tid  = threadIdx.x;
    const int wave = tid >> 6;
    const int cg   = wave >> 1;   // 0..7 col-group (32 gate cols)
    const int rg   = wave & 1;    // 0..1 row-group (16 batch rows)
    const int lane = tid & 63;
    const int q    = lane >> 4;
    const int ln   = lane & 15;
    const int b0   = blockIdx.x * 32;

    {   // zero h buffer 0 and both sbuf buffers
        bf16x8 z = {};
        bf16x8* p = (bf16x8*)hbuf;
        #pragma unroll 2
        for (int i = tid; i < HBUF_N / 8; i += 1024) p[i] = z;
        if (tid < 256) ((bf16x8*)sbuf)[tid] = z;
    }
    const int srow = tid >> 4, sk = tid & 15;   // rows 0..63; only srow<32 used

    // weight bases for this wave's col-group (A-operand rows; + jq offsets)
    const __bf16* wrB = Wg1   + (size_t)(cg * 32 + ln) * 288 + q * 8;        // + jq*4608
    const __bf16* wzB = Wg1   + (size_t)(256 + cg * 32 + ln) * 288 + q * 8;  // + jq*4608
    const __bf16* wxB = Win_n + (size_t)(cg * 32 + ln) * 32  + q * 8;        // + jq*512
    const __bf16* whB = Whh_n + (size_t)(cg * 32 + ln) * 256 + q * 8;        // + jq*4096
    const float*  bhnB = bhhn + cg * 32 + q * 4;                             // + jq*16

    const int row = rg * 16 + ln;
    const __bf16* hread = hbuf + row * HSTRIDE + q * 8;            // + kk*32, + SB*HBUF_N
    __bf16*       hwrt  = hbuf + row * HSTRIDE + cg * 32 + q * 4;  // + jq*16, + buf*HBUF_N
    const __bf16* sread = sbuf + row * 32 + q * 8;                 // + SB*1024
    __bf16*       rzw   = rzbuf + tid * 8;                         // + jq*8192

    // stage state slice v=0, then set the permanent 1.0 bias column (k=15)
    if (srow < 32 && sk < 15)
        sbuf[srow * 32 + sk] = (__bf16)state[(size_t)(b0 + srow) * 300 + sk];
    if (tid < 64) sbuf[(tid >> 5) * 1024 + (tid & 31) * 32 + 15] = (__bf16)1.0f;
    __syncthreads();

#define GRU_STEP(v, SB)                                                          \
    {                                                                            \
        float snext = 0.f;                                                       \
        if ((v) < 19 && srow < 32 && sk < 15)                                    \
            snext = state[(size_t)(b0 + srow) * 300 + ((v) + 1) * 15 + sk];      \
        _Pragma("unroll 1")                                                      \
        for (int p = 0; p < 2; ++p) {                                            \
            floatx4 acc0[2], acc1[2];                                            \
            const floatx4 zf = {0.f, 0.f, 0.f, 0.f};                             \
            acc0[0] = zf; acc0[1] = zf; acc1[0] = zf; acc1[1] = zf;               \
            if (p == 0) {                                                        \
                {                                                                \
                    bf16x8 b = *(const bf16x8*)(sread + (SB) * 1024);            \
                    _Pragma("unroll")                                            \
                    for (int jq = 0; jq < 2; jq++) {                             \
                        bf16x8 a0 = *(const bf16x8*)(wrB + jq * 4608);           \
                        bf16x8 a1 = *(const bf16x8*)(wzB + jq * 4608);           \
                        acc0[jq] = MFMA16(a0, b, acc0[jq]);                      \
                        acc1[jq] = MFMA16(a1, b, acc1[jq]);                      \
                    }                                                            \
                }                                                                \
                _Pragma("unroll")                                                \
                for (int kk = 0; kk < 8; ++kk) {                                 \
                    bf16x8 b = *(const bf16x8*)(hread + (SB) * HBUF_N +          \
                                                kk * 32);                        \
                    _Pragma("unroll")                                            \
                    for (int jq = 0; jq < 2; jq++) {                             \
                        bf16x8 a0 = *(const bf16x8*)(wrB + jq * 4608 + 32 +      \
                                                     kk * 32);                   \
                        bf16x8 a1 = *(const bf16x8*)(wzB + jq * 4608 + 32 +      \
                                                     kk * 32);                   \
                        acc0[jq] = MFMA16(a0, b, acc0[jq]);                      \
                        acc1[jq] = MFMA16(a1, b, acc1[jq]);                      \
                    }                                                            \
                }                                                                \
                _Pragma("unroll")                                                \
                for (int jq = 0; jq < 2; jq++) {                                 \
                    bf16x8 rz;                                                   \
                    _Pragma("unroll")                                            \
                    for (int r = 0; r < 4; r++) {                                \
                        rz[r]     = (__bf16)sigmoid_f(acc0[jq][r]);              \
                        rz[4 + r] = (__bf16)sigmoid_f(acc1[jq][r]);              \
                    }                                                            \
                    *(bf16x8*)(rzw + jq * 8192) = rz;                            \
                }                                                                \
            } else {                                                             \
                {                                                                \
                    bf16x8 b = *(const bf16x8*)(sread + (SB) * 1024);            \
                    _Pragma("unroll")                                            \
                    for (int jq = 0; jq < 2; jq++) {                             \
                        bf16x8 a = *(const bf16x8*)(wxB + jq * 512);             \
                        acc0[jq] = MFMA16(a, b, acc0[jq]);                       \
                    }                                                            \
                }                                                                \
                _Pragma("unroll")                                                \
                for (int kk = 0; kk < 8; ++kk) {                                 \
                    bf16x8 b = *(const bf16x8*)(hread + (SB) * HBUF_N +          \
                                                kk * 32);                        \
                    _Pragma("unroll")                                            \
                    for (int jq = 0; jq < 2; jq++) {                             \
                        bf16x8 a = *(const bf16x8*)(whB + jq * 4096 + kk * 32);  \
                        acc1[jq] = MFMA16(a, b, acc1[jq]);                       \
                    }                                                            \
                }                                                                \
                _Pragma("unroll")                                                \
                for (int jq = 0; jq < 2; jq++) {                                 \
                    bf16x8 rz = *(const bf16x8*)(rzw + jq * 8192);               \
                    floatx4 bh = *(const floatx4*)(bhnB + jq * 16);              \
                    bf16x4 ho = *(const bf16x4*)(hwrt + (SB) * HBUF_N +          \
                                                 jq * 16);                       \
                    bf16x4 hv;                                                   \
                    _Pragma("unroll")                                            \
                    for (int r = 0; r < 4; r++) {                                \
                        float rg_ = (float)rz[r];                                \
                        float zg  = (float)rz[4 + r];                            \
                        float nn = tanh_f(acc0[jq][r] +                          \
                                          rg_ * (acc1[jq][r] + bh[r]));          \
                        float hnew = (1.f - zg) * nn + zg * (float)ho[r];        \
                        hv[r] = (__bf16)hnew;                                    \
                    }                                                            \
                    *(bf16x4*)(hwrt + (1 - (SB)) * HBUF_N + jq * 16) = hv;       \
                }                                                                \
            }                                                                    \
        }                                                                        \
        if ((v) < 19 && srow < 32 && sk < 15)                                    \
            sbuf[(1 - (SB)) * 1024 + srow * 32 + sk] = (__bf16)snext;            \
        __syncthreads();                                                         \
    }

    #pragma unroll 1
    for (int v2 = 0; v2 < 10; ++v2) {
        GRU_STEP(2 * v2,     0)
        GRU_STEP(2 * v2 + 1, 1)
    }
#undef GRU_STEP

    // ---- epilogue: final h is in hbuf buffer 0 (step 19 wrote 1-SB = 0) ----
    // x0 = [state[:,0,:] (15) | 0-pad to 32 | h (256)], coalesced b128 moves.
    {
        const int erow = tid >> 5, p = tid & 31;   // 32 rows x 32 chunks
        *(bf16x8*)(x0 + (size_t)(b0 + erow) * 288 + 32 + p * 8) =
            *(const bf16x8*)(hbuf + erow * HSTRIDE + p * 8);
    }
    {
        const int erow = tid >> 5, c = tid & 31;
        float s = (c < 15) ? state[(size_t)(b0 + erow) * 300 + c] : 0.f;
        x0[(size_t)(b0 + erow) * 288 + c] = (__bf16)s;
    }
}

// ---------------------------------------------------------------------------
// m97-style LDS-staged GEMM: C = act(A[M][K] @ W[N][K]^T + bias), bf16, BK=32.
// 256 thr (4 waves 2x2), tile 128x128. Staging via global_load_lds width=16.
// Epilogue: LDS bounce -> coalesced stores.
// ---------------------------------------------------------------------------
__global__ __launch_bounds__(256)
void gemm_bias_act(const __bf16* __restrict__ A, const __bf16* __restrict__ W,
                   const float* __restrict__ bias, __bf16* __restrict__ C,
                   int N, int K, int relu)
{
    __shared__ __bf16 smem[128 * 136];           // 34816 B
    __bf16* At = smem;                           // [128][32]
    __bf16* Bt = smem + 4096;                    // [128][32]

    const int tid  = threadIdx.x;
    const int wave = tid >> 6, lane = tid & 63;
    const int q = lane >> 4, ln = lane & 15;
    const int wm = wave >> 1, wn = wave & 1;
    const int arow0 = blockIdx.x * 128;
    const int bcol0 = blockIdx.y * 128;

    float bv[4];
    #pragma unroll
    for (int n = 0; n < 4; n++) bv[n] = bias[bcol0 + wn * 64 + n * 16 + ln];

    floatx4 acc[4][4];
    const floatx4 zf = {0.f, 0.f, 0.f, 0.f};
    #pragma unroll
    for (int m = 0; m < 4; m++)
        #pragma unroll
        for (int n = 0; n < 4; n++) acc[m][n] = zf;

    const int stg_row = wave * 16 + (lane >> 2);
    const int stg_k   = (lane & 3) * 8;
    const int lds_off = wave * 512;

    for (int kt = 0; kt < K; kt += 32) {
        #pragma unroll
        for (int rd = 0; rd < 2; rd++) {
            GL_LDS16(A + (size_t)(arow0 + stg_row + rd * 64) * K + kt + stg_k,
                     At + lds_off + rd * 2048);
            GL_LDS16(W + (size_t)(bcol0 + stg_row + rd * 64) * K + kt + stg_k,
                     Bt + lds_off + rd * 2048);
        }
        __syncthreads();
        bf16x8 af[4], bf[4];
        #pragma unroll
        for (int m = 0; m < 4; m++)
            af[m] = *(const bf16x8*)(At + (wm * 64 + m * 16 + ln) * 32 + q * 8);
        #pragma unroll
        for (int n = 0; n < 4; n++)
            bf[n] = *(const bf16x8*)(Bt + (wn * 64 + n * 16 + ln) * 32 + q * 8);
        #pragma unroll
        for (int n = 0; n < 4; n++)
            #pragma unroll
            for (int m = 0; m < 4; m++)
                acc[m][n] = MFMA16(af[m], bf[n], acc[m][n]);
        __syncthreads();
    }

    #pragma unroll
    for (int m = 0; m < 4; m++)
        #pragma unroll
        for (int n = 0; n < 4; n++)
            #pragma unroll
            for (int r = 0; r < 4; r++) {
                float val = acc[m][n][r] + bv[n];
                if (relu) val = fmaxf(val, 0.f);
                smem[(wm * 64 + m * 16 + q * 4 + r) * 136 + wn * 64 + n * 16 + ln] = (__bf16)val;
            }
    __syncthreads();
    {
        const int row = tid >> 4, seg = tid & 15;
        #pragma unroll
        for (int p = 0; p < 8; p++) {
            const int rr = row + p * 16;
            *(bf16x8*)(C + (size_t)(arow0 + rr) * N + bcol0 + seg * 8) =
                *(const bf16x8*)(smem + rr * 136 + seg * 8);
        }
    }
}

// ---------------------------------------------------------------------------
// Head: out[b] = tanh(dot(x4[b][0..255], Wp) + bp).  4 lanes per row.
// ---------------------------------------------------------------------------
__global__ __launch_bounds__(256)
void head_kernel(const __bf16* __restrict__ x4, const float* __restrict__ Wp,
                 const float* __restrict__ bp, float* __restrict__ out)
{
    const int tid = threadIdx.x;
    const int wave = tid >> 6, lane = tid & 63;
    const int row = blockIdx.x * 64 + wave * 16 + (lane >> 2);
    const int part = lane & 3;
    const __bf16* xp = x4 + (size_t)row * 256 + part * 64;
    const float* wp = Wp + part * 64;
    float sum = 0.f;
    #pragma unroll
    for (int i = 0; i < 8; i++) {
        bf16x8 xv = *(const bf16x8*)(xp + i * 8);
        #pragma unroll
        for (int jj = 0; jj < 8; jj++) sum += (float)xv[jj] * wp[i * 8 + jj];
    }
    sum += __shfl_xor(sum, 1);
    sum += __shfl_xor(sum, 2);
    if (part == 0) out[row] = tanhf(sum + bp[0]);
}

// ---------------------------------------------------------------------------
extern "C" void kernel_launch(void* const* d_in, const int* in_sizes, int n_in,
                              void* d_out, int out_size, void* d_ws, size_t ws_size,
                              hipStream_t stream)
{
    const float* state = (const float*)d_in[0];
    const float* W_ih  = (const float*)d_in[1];
    const float* W_hh  = (const float*)d_in[2];
    const float* b_ih  = (const float*)d_in[3];
    const float* b_hh  = (const float*)d_in[4];
    const float* W1    = (const float*)d_in[5];
    const float* b1    = (const float*)d_in[6];
    const float* W2    = (const float*)d_in[7];
    const float* b2    = (const float*)d_in[8];
    const float* W3    = (const float*)d_in[9];
    const float* b3    = (const float*)d_in[10];
    const float* W4    = (const float*)d_in[11];
    const float* b4    = (const float*)d_in[12];
    const float* Wp    = (const float*)d_in[13];
    const float* bp    = (const float*)d_in[14];
    float* out = (float*)d_out;

    char* ws = (char*)d_ws;
    size_t off = 0;
    auto alloc = [&](size_t bytes) -> void* {
        void* p = ws + off;
        off += (bytes + 255) & ~(size_t)255;
        return p;
    };
    __bf16* Wg1   = (__bf16*)alloc(512 * 288 * 2);
    __bf16* W1p   = (__bf16*)alloc(1024 * 288 * 2);
    __bf16* W2b   = (__bf16*)alloc(1024 * 1024 * 2);
    __bf16* W3b   = (__bf16*)alloc(512 * 1024 * 2);
    __bf16* W4b   = (__bf16*)alloc(256 * 512 * 2);
    __bf16* Win_n = (__bf16*)alloc(256 * 32 * 2);
    __bf16* Whh_n = (__bf16*)alloc(256 * 256 * 2);
    float*  bsum  = (float*)alloc(512 * 4);
    float*  bihn  = (float*)alloc(256 * 4);
    float*  bhhn  = (float*)alloc(256 * 4);
    __bf16* x0    = (__bf16*)alloc((size_t)16384 * 288 * 2);
    __bf16* xA    = (__bf16*)alloc((size_t)16384 * 1024 * 2);
    __bf16* xB    = (__bf16*)alloc((size_t)16384 * 1024 * 2);

    prep_kernel<<<2048, 256, 0, stream>>>(W_ih, W_hh, b_ih, b_hh, W1, W2, W3, W4,
                                          Wg1, W1p, W2b, W3b, W4b, Win_n, Whh_n,
                                          bsum, bihn, bhhn);
    gru_kernel<<<512, 1024, 0, stream>>>(state, Wg1, Win_n, Whh_n, bhhn, x0);
    gemm_bias_act<<<dim3(128, 8), 256, 0, stream>>>(x0, W1p, b1, xA, 1024, 288, 1);
    gemm_bias_act<<<dim3(128, 8), 256, 0, stream>>>(xA, W2b, b2, xB, 1024, 1024, 1);
    gemm_bias_act<<<dim3(128, 4), 256, 0, stream>>>(xB, W3b, b3, xA, 512, 1024, 1);
    gemm_bias_act<<<dim3(128, 2), 256, 0, stream>>>(xA, W4b, b4, xB, 256, 512, 1);
    head_kernel<<<256, 256, 0, stream>>>(xB, Wp, bp, out);
}

// Round 14
// 456.863 us; speedup vs baseline: 2.7279x; 1.9140x over previous
//
#include <hip/hip_runtime.h>

// ---------------------------------------------------------------------------
// Actor: GRU over V=20 vehicle slots (H=256) + MLP head 271->1024->1024->512->256->1
// B=16384, F=15. All GEMMs in bf16 MFMA (16x16x32), fp32 accumulate.
//
// Round-14: revert GRU to r11 (best known: 297 us GRU / 463 total). r12/r13
// proved r11's tiling optimal under the empirical 64-VGPR wg-1024 budget:
// 16 j-cols/wave minimizes weight VMEM issue; 2 blocks/CU is unavailable
// (1024-thr blocks never pair). Deltas vs r11: sbuf stride 32->40 (state-
// slice reads now conflict-free) and GEMM BK=64 (halved barrier count).
// ---------------------------------------------------------------------------

typedef __attribute__((ext_vector_type(8))) __bf16 bf16x8;
typedef __attribute__((ext_vector_type(4))) __bf16 bf16x4;
typedef __attribute__((ext_vector_type(4))) float  floatx4;

#define MFMA16(a, b, c) __builtin_amdgcn_mfma_f32_16x16x32_bf16((a), (b), (c), 0, 0, 0)

#define GL_LDS16(g, l)                                                         \
    __builtin_amdgcn_global_load_lds(                                          \
        (const __attribute__((address_space(1))) void*)(g),                    \
        (__attribute__((address_space(3))) void*)(l), 16, 0, 0)

__device__ __forceinline__ float sigmoid_f(float x) { return 1.f / (1.f + __expf(-x)); }
__device__ __forceinline__ float tanh_f(float x)    { return 1.f - 2.f / (1.f + __expf(2.f * x)); }

// ---------------------------------------------------------------------------
// Weight prep:
//   Wg1  [512][288]  rows g in {r(0..255), z(256..511)}:
//        [W_ih[g][0..14] | bsum[g] | 0 x16 | W_hh[g][0..255]]   (col 15 = bias)
//   W1p  [1024][288] : [W1[o][0..14] | 0 x17 | W1[o][15..270]]
//   W2b  [1024][1024], W3b [512][1024], W4b [256][512]  : direct cvt
//   Win_n[256][32]   : [W_ih[512+j][0..14] | b_ih[512+j] | 0 x16] (col 15 = bias)
//   Whh_n[256][256]  : W_hh rows 512..767
//   bhhn [256] = b_hh[512+]
// ---------------------------------------------------------------------------
#define S0 147456u
#define S1 442368u
#define S2 1490944u
#define S3 2015232u
#define S4 2146304u
#define S5 2154496u
#define S6 2220032u
#define S7 2220544u
#define S8 2221056u

__global__ void prep_kernel(const float* __restrict__ W_ih, const float* __restrict__ W_hh,
                            const float* __restrict__ b_ih, const float* __restrict__ b_hh,
                            const float* __restrict__ W1, const float* __restrict__ W2,
                            const float* __restrict__ W3, const float* __restrict__ W4,
                            __bf16* __restrict__ Wg1, __bf16* __restrict__ W1p,
                            __bf16* __restrict__ W2b, __bf16* __restrict__ W3b,
                            __bf16* __restrict__ W4b, __bf16* __restrict__ Win_n,
                            __bf16* __restrict__ Whh_n, float* __restrict__ bsum,
                            float* __restrict__ bihn, float* __restrict__ bhhn)
{
    for (unsigned i = blockIdx.x * blockDim.x + threadIdx.x; i < S8; i += gridDim.x * blockDim.x) {
        if (i < S0) {
            unsigned g = i / 288u, c = i % 288u;
            float v;
            if (c < 15u)       v = W_ih[g * 15u + c];
            else if (c == 15u) v = b_ih[g] + b_hh[g];          // folded r/z bias
            else if (c < 32u)  v = 0.f;
            else               v = W_hh[g * 256u + (c - 32u)];
            Wg1[i] = (__bf16)v;
        } else if (i < S1) {
            unsigned t = i - S0, o = t / 288u, c = t % 288u;
            float v = (c < 15u) ? W1[o * 271u + c] : ((c < 32u) ? 0.f : W1[o * 271u + (c - 17u)]);
            W1p[t] = (__bf16)v;
        } else if (i < S2) {
            unsigned t = i - S1; W2b[t] = (__bf16)W2[t];
        } else if (i < S3) {
            unsigned t = i - S2; W3b[t] = (__bf16)W3[t];
        } else if (i < S4) {
            unsigned t = i - S3; W4b[t] = (__bf16)W4[t];
        } else if (i < S5) {
            unsigned t = i - S4, j = t / 32u, c = t % 32u;
            float v;
            if (c < 15u)       v = W_ih[(512u + j) * 15u + c];
            else if (c == 15u) v = b_ih[512u + j];             // folded xn bias
            else               v = 0.f;
            Win_n[t] = (__bf16)v;
        } else if (i < S6) {
            unsigned t = i - S5; Whh_n[t] = (__bf16)W_hh[512u * 256u + t];
        } else if (i < S7) {
            unsigned t = i - S6; bsum[t] = b_ih[t] + b_hh[t];
        } else {
            unsigned t = i - S7;
            if (t < 256u) bihn[t] = b_ih[512u + t];
            else          bhhn[t - 256u] = b_hh[512u + t - 256u];
        }
    }
}

// ---------------------------------------------------------------------------
// GRU kernel (r11). 256 blocks x 1024 threads (16 waves). 64 batch rows/block.
// Wave w owns gate cols w*16..w*16+15. Per step, 2 unroll-1 passes:
//   p0: acc (ar,az) over all 4 nt (32 regs) -> sigmoid -> rzbuf[nt][tid]
//   p1: acc (axn,ahn) (32 regs) -> n=tanh(axn+r*(ahn+bhn)), h'=(1-z)n+z*h_old
// hbuf[2][64][264] double-buffered, 1 barrier/step. sbuf stride 40 (was 32):
// 5*ln+q mod 8 covers all 8 bank groups -> conflict-free state reads.
// ---------------------------------------------------------------------------
#define HSTRIDE 264
#define HBUF_N  (64 * HSTRIDE)
#define SSTRIDE 40
#define SBUF_N  (64 * SSTRIDE)    // 2560 per buffer

__global__ __launch_bounds__(1024)
void gru_kernel(const float* __restrict__ state,
                const __bf16* __restrict__ Wg1,  const __bf16* __restrict__ Win_n,
                const __bf16* __restrict__ Whh_n,
                const float* __restrict__ bhhn, __bf16* __restrict__ x0)
{
    __shared__ __bf16 hbuf[2 * HBUF_N];        // 67584 B
    __shared__ __bf16 sbuf[2 * SBUF_N];        // 10240 B; k 16..39 zero, k15 = 1.0
    __shared__ __bf16 rzbuf[4 * 1024 * 8];     // 65536 B: [nt][tid][8] r0..3|z0..3

    const int tid  = threadIdx.x;
    const int wave = tid >> 6;    // 0..15 : j-tile
    const int lane = tid & 63;
    const int q    = lane >> 4;
    const int ln   = lane & 15;
    const int b0   = blockIdx.x * 64;

    {   // zero h buffer 0 and both sbuf buffers
        bf16x8 z = {};
        bf16x8* p = (bf16x8*)hbuf;
        #pragma unroll 3
        for (int i = tid; i < HBUF_N / 8; i += 1024) p[i] = z;
        if (tid < 2 * SBUF_N / 8) ((bf16x8*)sbuf)[tid] = z;
    }
    const int srow = tid >> 4, sk = tid & 15;   // 64 rows x 16 cols staging

    // bhn (other biases folded into weight col 15 against sbuf's 1.0 column)
    const floatx4 Bhn = *(const floatx4*)(bhhn + wave * 16 + q * 4);

    const int jr = wave * 16 + ln;
    const __bf16* wr = Wg1   + (size_t)jr * 288 + q * 8;
    const __bf16* wz = Wg1   + (size_t)(256 + jr) * 288 + q * 8;
    const __bf16* wx = Win_n + (size_t)jr * 32  + q * 8;
    const __bf16* wh = Whh_n + (size_t)jr * 256 + q * 8;

    const __bf16* hread  = hbuf + ln * HSTRIDE + q * 8;              // + nt*16*HSTRIDE
    __bf16*       hwrite = hbuf + ln * HSTRIDE + wave * 16 + q * 4;  // + nt*16*HSTRIDE
    const __bf16* sread  = sbuf + ln * SSTRIDE + q * 8;              // + nt*16*SSTRIDE
    __bf16*       rzw    = rzbuf + tid * 8;                          // + nt*8192

    // stage state slice v=0, then set the permanent 1.0 bias column (k=15)
    if (sk < 15)
        sbuf[srow * SSTRIDE + sk] = (__bf16)state[(size_t)(b0 + srow) * 300 + sk];
    if (tid < 128) sbuf[(tid >> 6) * SBUF_N + (tid & 63) * SSTRIDE + 15] = (__bf16)1.0f;
    __syncthreads();

#define GRU_STEP(v, SB)                                                          \
    {                                                                            \
        float snext = 0.f;                                                       \
        if ((v) < 19 && sk < 15)                                                 \
            snext = state[(size_t)(b0 + srow) * 300 + ((v) + 1) * 15 + sk];      \
        _Pragma("unroll 1")                                                      \
        for (int p = 0; p < 2; ++p) {                                            \
            floatx4 acc0[4], acc1[4];                                            \
            const floatx4 zf = {0.f, 0.f, 0.f, 0.f};                             \
            _Pragma("unroll")                                                    \
            for (int nt = 0; nt < 4; nt++) { acc0[nt] = zf; acc1[nt] = zf; }     \
            if (p == 0) {                                                        \
                {                                                                \
                    bf16x8 a0 = *(const bf16x8*)(wr);                            \
                    bf16x8 a1 = *(const bf16x8*)(wz);                            \
                    _Pragma("unroll")                                            \
                    for (int nt = 0; nt < 4; nt++) {                             \
                        bf16x8 b = *(const bf16x8*)(sread + (SB) * SBUF_N +      \
                                                    nt * (16 * SSTRIDE));        \
                        acc0[nt] = MFMA16(a0, b, acc0[nt]);                      \
                        acc1[nt] = MFMA16(a1, b, acc1[nt]);                      \
                    }                                                            \
                }                                                                \
                _Pragma("unroll")                                                \
                for (int kk = 0; kk < 8; ++kk) {                                 \
                    bf16x8 a0 = *(const bf16x8*)(wr + 32 + kk * 32);             \
                    bf16x8 a1 = *(const bf16x8*)(wz + 32 + kk * 32);             \
                    _Pragma("unroll")                                            \
                    for (int nt = 0; nt < 4; nt++) {                             \
                        bf16x8 b = *(const bf16x8*)(hread + (SB) * HBUF_N +      \
                                                    nt * (16 * HSTRIDE) +        \
                                                    kk * 32);                    \
                        acc0[nt] = MFMA16(a0, b, acc0[nt]);                      \
                        acc1[nt] = MFMA16(a1, b, acc1[nt]);                      \
                    }                                                            \
                }                                                                \
                _Pragma("unroll")                                                \
                for (int nt = 0; nt < 4; nt++) {                                 \
                    bf16x8 rz;                                                   \
                    _Pragma("unroll")                                            \
                    for (int r = 0; r < 4; r++) {                                \
                        rz[r]     = (__bf16)sigmoid_f(acc0[nt][r]);              \
                        rz[4 + r] = (__bf16)sigmoid_f(acc1[nt][r]);              \
                    }                                                            \
                    *(bf16x8*)(rzw + nt * 8192) = rz;                            \
                }                                                                \
            } else {                                                             \
                {                                                                \
                    bf16x8 a0 = *(const bf16x8*)(wx);                            \
                    _Pragma("unroll")                                            \
                    for (int nt = 0; nt < 4; nt++) {                             \
                        bf16x8 b = *(const bf16x8*)(sread + (SB) * SBUF_N +      \
                                                    nt * (16 * SSTRIDE));        \
                        acc0[nt] = MFMA16(a0, b, acc0[nt]);                      \
                    }                                                            \
                }                                                                \
                _Pragma("unroll")                                                \
                for (int kk = 0; kk < 8; ++kk) {                                 \
                    bf16x8 a1 = *(const bf16x8*)(wh + kk * 32);                  \
                    _Pragma("unroll")                                            \
                    for (int nt = 0; nt < 4; nt++) {                             \
                        bf16x8 b = *(const bf16x8*)(hread + (SB) * HBUF_N +      \
                                                    nt * (16 * HSTRIDE) +        \
                                                    kk * 32);                    \
                        acc1[nt] = MFMA16(a1, b, acc1[nt]);                      \
                    }                                                            \
                }                                                                \
                _Pragma("unroll")                                                \
                for (int nt = 0; nt < 4; nt++) {                                 \
                    bf16x8 rz = *(const bf16x8*)(rzw + nt * 8192);               \
                    bf16x4 ho = *(const bf16x4*)(hwrite + (SB) * HBUF_N +        \
                                                 nt * (16 * HSTRIDE));           \
                    bf16x4 hv;                                                   \
                    _Pragma("unroll")                                            \
                    for (int r = 0; r < 4; r++) {                                \
                        float rg = (float)rz[r];                                 \
                        float zg = (float)rz[4 + r];                             \
                        float nn = tanh_f(acc0[nt][r] +                          \
                                          rg * (acc1[nt][r] + Bhn[r]));          \
                        float hnew = (1.f - zg) * nn + zg * (float)ho[r];        \
                        hv[r] = (__bf16)hnew;                                    \
                    }                                                            \
                    *(bf16x4*)(hwrite + (1 - (SB)) * HBUF_N +                    \
                               nt * (16 * HSTRIDE)) = hv;                        \
                }                                                                \
            }                                                                    \
        }                                                                        \
        if ((v) < 19 && sk < 15)                                                 \
            sbuf[(1 - (SB)) * SBUF_N + srow * SSTRIDE + sk] = (__bf16)snext;     \
        __syncthreads();                                                         \
    }

    #pragma unroll 1
    for (int v2 = 0; v2 < 10; ++v2) {
        GRU_STEP(2 * v2,     0)
        GRU_STEP(2 * v2 + 1, 1)
    }
#undef GRU_STEP

    // ---- epilogue: final h is in hbuf buffer 0 (step 19 wrote 1-SB = 0) ----
    // x0 = [state[:,0,:] (15) | 0-pad to 32 | h (256)], coalesced b128 moves.
    {
        const int erow = tid >> 4, p = tid & 15;
        #pragma unroll
        for (int s = 0; s < 2; s++) {
            const int col = p * 8 + s * 128;
            *(bf16x8*)(x0 + (size_t)(b0 + erow) * 288 + 32 + col) =
                *(const bf16x8*)(hbuf + erow * HSTRIDE + col);
        }
    }
    #pragma unroll
    for (int t = 0; t < 2; t++) {
        int i = tid + t * 1024;
        int erow = i >> 5, c = i & 31;
        float s = (c < 15) ? state[(size_t)(b0 + erow) * 300 + c] : 0.f;
        x0[(size_t)(b0 + erow) * 288 + c] = (__bf16)s;
    }
}

// ---------------------------------------------------------------------------
// LDS-staged GEMM, BK=64: C = act(A[M][K] @ W[N][K]^T + bias), bf16.
// 256 thr (4 waves 2x2), tile 128x128. Staging: 8 global_load_lds(16B)
// rounds per 64-k slab (two 32-k halves), ONE barrier pair per slab (halves
// r11's barrier count). K tail of 32 supported (gemm1 K=288).
// LDS: staging 32 KB inside the 34.8 KB bounce union.
// ---------------------------------------------------------------------------
__global__ __launch_bounds__(256)
void gemm_bias_act(const __bf16* __restrict__ A, const __bf16* __restrict__ W,
                   const float* __restrict__ bias, __bf16* __restrict__ C,
                   int N, int K, int relu)
{
    __shared__ __bf16 smem[128 * 136];           // 34816 B
    // staging layout: A-lo [128][32] @0, A-hi @4096, B-lo @8192, B-hi @12288

    const int tid  = threadIdx.x;
    const int wave = tid >> 6, lane = tid & 63;
    const int q = lane >> 4, ln = lane & 15;
    const int wm = wave >> 1, wn = wave & 1;
    const int arow0 = blockIdx.x * 128;
    const int bcol0 = blockIdx.y * 128;

    float bv[4];
    #pragma unroll
    for (int n = 0; n < 4; n++) bv[n] = bias[bcol0 + wn * 64 + n * 16 + ln];

    floatx4 acc[4][4];
    const floatx4 zf = {0.f, 0.f, 0.f, 0.f};
    #pragma unroll
    for (int m = 0; m < 4; m++)
        #pragma unroll
        for (int n = 0; n < 4; n++) acc[m][n] = zf;

    const int stg_row = wave * 16 + (lane >> 2);   // + rd*64
    const int stg_k   = (lane & 3) * 8;            // + h*32
    const int lds_off = wave * 512;                // + rd*2048, + h*4096

    int kt = 0;
    for (; kt + 64 <= K; kt += 64) {
        #pragma unroll
        for (int h = 0; h < 2; h++)
            #pragma unroll
            for (int rd = 0; rd < 2; rd++) {
                GL_LDS16(A + (size_t)(arow0 + stg_row + rd * 64) * K + kt + h * 32 + stg_k,
                         smem + h * 4096 + lds_off + rd * 2048);
                GL_LDS16(W + (size_t)(bcol0 + stg_row + rd * 64) * K + kt + h * 32 + stg_k,
                         smem + 8192 + h * 4096 + lds_off + rd * 2048);
            }
        __syncthreads();
        #pragma unroll
        for (int h = 0; h < 2; h++) {
            bf16x8 af[4], bf[4];
            #pragma unroll
            for (int m = 0; m < 4; m++)
                af[m] = *(const bf16x8*)(smem + h * 4096 + (wm * 64 + m * 16 + ln) * 32 + q * 8);
            #pragma unroll
            for (int n = 0; n < 4; n++)
                bf[n] = *(const bf16x8*)(smem + 8192 + h * 4096 + (wn * 64 + n * 16 + ln) * 32 + q * 8);
            #pragma unroll
            for (int n = 0; n < 4; n++)
                #pragma unroll
                for (int m = 0; m < 4; m++)
                    acc[m][n] = MFMA16(af[m], bf[n], acc[m][n]);
        }
        __syncthreads();
    }
    if (kt < K) {   // 32-k tail
        #pragma unroll
        for (int rd = 0; rd < 2; rd++) {
            GL_LDS16(A + (size_t)(arow0 + stg_row + rd * 64) * K + kt + stg_k,
                     smem + lds_off + rd * 2048);
            GL_LDS16(W + (size_t)(bcol0 + stg_row + rd * 64) * K + kt + stg_k,
                     smem + 8192 + lds_off + rd * 2048);
        }
        __syncthreads();
        bf16x8 af[4], bf[4];
        #pragma unroll
        for (int m = 0; m < 4; m++)
            af[m] = *(const bf16x8*)(smem + (wm * 64 + m * 16 + ln) * 32 + q * 8);
        #pragma unroll
        for (int n = 0; n < 4; n++)
            bf[n] = *(const bf16x8*)(smem + 8192 + (wn * 64 + n * 16 + ln) * 32 + q * 8);
        #pragma unroll
        for (int n = 0; n < 4; n++)
            #pragma unroll
            for (int m = 0; m < 4; m++)
                acc[m][n] = MFMA16(af[m], bf[n], acc[m][n]);
        __syncthreads();
    }

    // epilogue: bias+act -> LDS bounce (stride 136) -> coalesced b128 stores
    #pragma unroll
    for (int m = 0; m < 4; m++)
        #pragma unroll
        for (int n = 0; n < 4; n++)
            #pragma unroll
            for (int r = 0; r < 4; r++) {
                float val = acc[m][n][r] + bv[n];
                if (relu) val = fmaxf(val, 0.f);
                smem[(wm * 64 + m * 16 + q * 4 + r) * 136 + wn * 64 + n * 16 + ln] = (__bf16)val;
            }
    __syncthreads();
    {
        const int row = tid >> 4, seg = tid & 15;
        #pragma unroll
        for (int p = 0; p < 8; p++) {
            const int rr = row + p * 16;
            *(bf16x8*)(C + (size_t)(arow0 + rr) * N + bcol0 + seg * 8) =
                *(const bf16x8*)(smem + rr * 136 + seg * 8);
        }
    }
}

// ---------------------------------------------------------------------------
// Head: out[b] = tanh(dot(x4[b][0..255], Wp) + bp).  4 lanes per row.
// ---------------------------------------------------------------------------
__global__ __launch_bounds__(256)
void head_kernel(const __bf16* __restrict__ x4, const float* __restrict__ Wp,
                 const float* __restrict__ bp, float* __restrict__ out)
{
    const int tid = threadIdx.x;
    const int wave = tid >> 6, lane = tid & 63;
    const int row = blockIdx.x * 64 + wave * 16 + (lane >> 2);
    const int part = lane & 3;
    const __bf16* xp = x4 + (size_t)row * 256 + part * 64;
    const float* wp = Wp + part * 64;
    float sum = 0.f;
    #pragma unroll
    for (int i = 0; i < 8; i++) {
        bf16x8 xv = *(const bf16x8*)(xp + i * 8);
        #pragma unroll
        for (int jj = 0; jj < 8; jj++) sum += (float)xv[jj] * wp[i * 8 + jj];
    }
    sum += __shfl_xor(sum, 1);
    sum += __shfl_xor(sum, 2);
    if (part == 0) out[row] = tanhf(sum + bp[0]);
}

// ---------------------------------------------------------------------------
extern "C" void kernel_launch(void* const* d_in, const int* in_sizes, int n_in,
                              void* d_out, int out_size, void* d_ws, size_t ws_size,
                              hipStream_t stream)
{
    const float* state = (const float*)d_in[0];
    const float* W_ih  = (const float*)d_in[1];
    const float* W_hh  = (const float*)d_in[2];
    const float* b_ih  = (const float*)d_in[3];
    const float* b_hh  = (const float*)d_in[4];
    const float* W1    = (const float*)d_in[5];
    const float* b1    = (const float*)d_in[6];
    const float* W2    = (const float*)d_in[7];
    const float* b2    = (const float*)d_in[8];
    const float* W3    = (const float*)d_in[9];
    const float* b3    = (const float*)d_in[10];
    const float* W4    = (const float*)d_in[11];
    const float* b4    = (const float*)d_in[12];
    const float* Wp    = (const float*)d_in[13];
    const float* bp    = (const float*)d_in[14];
    float* out = (float*)d_out;

    char* ws = (char*)d_ws;
    size_t off = 0;
    auto alloc = [&](size_t bytes) -> void* {
        void* p = ws + off;
        off += (bytes + 255) & ~(size_t)255;
        return p;
    };
    __bf16* Wg1   = (__bf16*)alloc(512 * 288 * 2);
    __bf16* W1p   = (__bf16*)alloc(1024 * 288 * 2);
    __bf16* W2b   = (__bf16*)alloc(1024 * 1024 * 2);
    __bf16* W3b   = (__bf16*)alloc(512 * 1024 * 2);
    __bf16* W4b   = (__bf16*)alloc(256 * 512 * 2);
    __bf16* Win_n = (__bf16*)alloc(256 * 32 * 2);
    __bf16* Whh_n = (__bf16*)alloc(256 * 256 * 2);
    float*  bsum  = (float*)alloc(512 * 4);
    float*  bihn  = (float*)alloc(256 * 4);
    float*  bhhn  = (float*)alloc(256 * 4);
    __bf16* x0    = (__bf16*)alloc((size_t)16384 * 288 * 2);
    __bf16* xA    = (__bf16*)alloc((size_t)16384 * 1024 * 2);
    __bf16* xB    = (__bf16*)alloc((size_t)16384 * 1024 * 2);

    prep_kernel<<<2048, 256, 0, stream>>>(W_ih, W_hh, b_ih, b_hh, W1, W2, W3, W4,
                                          Wg1, W1p, W2b, W3b, W4b, Win_n, Whh_n,
                                          bsum, bihn, bhhn);
    gru_kernel<<<256, 1024, 0, stream>>>(state, Wg1, Win_n, Whh_n, bhhn, x0);
    gemm_bias_act<<<dim3(128, 8), 256, 0, stream>>>(x0, W1p, b1, xA, 1024, 288, 1);
    gemm_bias_act<<<dim3(128, 8), 256, 0, stream>>>(xA, W2b, b2, xB, 1024, 1024, 1);
    gemm_bias_act<<<dim3(128, 4), 256, 0, stream>>>(xB, W3b, b3, xA, 512, 1024, 1);
    gemm_bias_act<<<dim3(128, 2), 256, 0, stream>>>(xA, W4b, b4, xB, 256, 512, 1);
    head_kernel<<<256, 256, 0, stream>>>(xB, Wp, bp, out);
}